// Round 15
// baseline (61.265 us; speedup 1.0000x reference)
//
#include <hip/hip_runtime.h>

// Problem constants (from reference setup_inputs)
#define BZ 4
#define H 192
#define W 640
#define PIX (H * W)            // 122880 pixels per batch
#define MAXINS 200
#define CAND 16
#define CE 36                  // ch*cw
#define CE4 9                  // float4 groups per pixel
#define BATCH_FLOATS (MAXINS * CE)          // 7200 floats per batch
#define BATCH_F4     (BATCH_FLOATS / 4)     // 1800 float4 per batch
#define COMP_FLOATS (BZ * BATCH_FLOATS)     // 28800 floats
#define COMP_BYTES  (COMP_FLOATS * 4)       // 115200 bytes
#define BPB 192                             // blocks per batch
#define NBLK (BZ * BPB)                     // 768 compress blocks
#define STRIPE (PIX / BPB)                  // 640 contiguous pixels per block
#define TPB 512                             // threads per block
#define ITEMS 4                             // ceil(1800/512) per-thread items
#define PART_BYTES ((size_t)NBLK * BATCH_FLOATS * 4)   // 22.1 MB

// ============ compress: block-local counting sort, NO fp atomics =========
// r11/r12: latency-bound in phase 2 (~4-deep MLP). This round: 2x-unrolled
// double-buffered gather -> 8 outstanding VMEM loads per thread.
// __launch_bounds__(512,6): 6 waves/SIMD -> VGPR cap ~85, keeps 3 blocks/CU.

__global__ __launch_bounds__(TPB, 6) void compress_sort_kernel(
        const int* __restrict__ inst,
        const float4* __restrict__ compsrc,
        float4* __restrict__ partials) {
    __shared__ unsigned char  mloc[STRIPE];     // per-pixel m (cached)
    __shared__ unsigned short sorted[STRIPE];   // local pixel ids, grouped by m
    __shared__ int cnt[MAXINS];
    __shared__ int off[MAXINS + 1];
    __shared__ int off_run[MAXINS];
    __shared__ int tmp[TPB];

    const int b    = blockIdx.x / BPB;
    const int blk  = blockIdx.x % BPB;
    const int tid  = threadIdx.x;
    const int pix0 = blk * STRIPE;

    if (tid < MAXINS) cnt[tid] = 0;
    __syncthreads();

    // ---- count pass: 640 int LDS atomics, cache m ----
    for (int p = tid; p < STRIPE; p += TPB) {
        int m = inst[b * PIX + pix0 + p];       // coalesced
        mloc[p] = (unsigned char)m;
        atomicAdd(&cnt[m], 1);                  // ds_add_u32
    }
    __syncthreads();

    // ---- exclusive scan cnt -> off (Hillis-Steele, TPB-wide, uniform syncs) ----
    int c = (tid < MAXINS) ? cnt[tid] : 0;
    tmp[tid] = c;
    __syncthreads();
    for (int s = 1; s < TPB; s <<= 1) {
        int v = (tid >= s) ? tmp[tid - s] : 0;
        __syncthreads();
        tmp[tid] += v;
        __syncthreads();
    }
    if (tid < MAXINS) { off[tid] = tmp[tid] - c; off_run[tid] = tmp[tid] - c; }
    if (tid == 0) off[MAXINS] = STRIPE;
    __syncthreads();

    // ---- scatter local pixel ids into m-sorted order ----
    for (int p = tid; p < STRIPE; p += TPB) {
        int slot = atomicAdd(&off_run[mloc[p]], 1);   // ds_add_rtn_u32
        sorted[slot] = (unsigned short)p;
    }
    __syncthreads();

    // ---- phase 2: per-(m,e4) register accumulation, 2x double-buffered ----
    // item = m*9 + e4; 9 consecutive lanes read the same pixel's contiguous
    // 144B. 8 loads (4 items x 2 iterations) in flight before first use.
    const float4* src = compsrc + (size_t)(b * PIX + pix0) * CE4;
    float4 acc[ITEMS];
    int base_[ITEMS], len_[ITEMS], e4_[ITEMS], ia[ITEMS], ib[ITEMS];
    int maxlen = 0;
    #pragma unroll
    for (int j = 0; j < ITEMS; ++j) {
        const int item = tid + TPB * j;
        acc[j] = make_float4(0.f, 0.f, 0.f, 0.f);
        if (item < BATCH_F4) {
            const int m  = item / CE4;
            e4_[j]   = item - m * CE4;
            base_[j] = off[m];
            len_[j]  = off[m + 1] - off[m];
            maxlen   = len_[j] > maxlen ? len_[j] : maxlen;
        } else { base_[j] = 0; len_[j] = 0; e4_[j] = 0; }
        ia[j] = (0 < len_[j]) ? (int)sorted[base_[j]] : 0;
        ib[j] = (1 < len_[j]) ? (int)sorted[base_[j] + 1] : 0;
    }
    int i = 0;
    for (; i + 1 < maxlen; i += 2) {
        float4 va[ITEMS], vb[ITEMS];
        #pragma unroll
        for (int j = 0; j < ITEMS; ++j)            // issue 4 loads (iter i)
            if (i < len_[j]) va[j] = src[(size_t)ia[j] * CE4 + e4_[j]];
        #pragma unroll
        for (int j = 0; j < ITEMS; ++j)            // issue 4 loads (iter i+1)
            if (i + 1 < len_[j]) vb[j] = src[(size_t)ib[j] * CE4 + e4_[j]];
        #pragma unroll
        for (int j = 0; j < ITEMS; ++j) {          // LDS prefetch i+2, i+3
            ia[j] = (i + 2 < len_[j]) ? (int)sorted[base_[j] + i + 2] : 0;
            ib[j] = (i + 3 < len_[j]) ? (int)sorted[base_[j] + i + 3] : 0;
        }
        #pragma unroll
        for (int j = 0; j < ITEMS; ++j)
            if (i < len_[j]) {
                acc[j].x += va[j].x; acc[j].y += va[j].y;
                acc[j].z += va[j].z; acc[j].w += va[j].w;
            }
        #pragma unroll
        for (int j = 0; j < ITEMS; ++j)
            if (i + 1 < len_[j]) {
                acc[j].x += vb[j].x; acc[j].y += vb[j].y;
                acc[j].z += vb[j].z; acc[j].w += vb[j].w;
            }
    }
    if (i < maxlen) {                              // odd tail
        float4 va[ITEMS];
        #pragma unroll
        for (int j = 0; j < ITEMS; ++j)
            if (i < len_[j]) va[j] = src[(size_t)ia[j] * CE4 + e4_[j]];
        #pragma unroll
        for (int j = 0; j < ITEMS; ++j)
            if (i < len_[j]) {
                acc[j].x += va[j].x; acc[j].y += va[j].y;
                acc[j].z += va[j].z; acc[j].w += va[j].w;
            }
    }

    // ---- store full partial (zeros included): every byte overwritten ----
    float4* p = partials + (size_t)blockIdx.x * BATCH_F4;
    #pragma unroll
    for (int j = 0; j < ITEMS; ++j) {
        const int item = tid + TPB * j;
        if (item < BATCH_F4) p[item] = acc[j];           // coalesced
    }
}

// comp[t4] = sel gather + sum over the BPB partial slots of batch b
__global__ void reduce_priv_kernel(const float4* __restrict__ partials,
                                   const int* __restrict__ batchidx,
                                   const float4* __restrict__ selsrc,
                                   float4* __restrict__ comp) {
    const int t = blockIdx.x * blockDim.x + threadIdx.x;   // over 7200 float4
    if (t >= COMP_FLOATS / 4) return;
    const int e4 = t % CE4;
    const int bm = t / CE4;                    // b*MAXINS + m
    const int b  = t / BATCH_F4;
    const int j  = t - b * BATCH_F4;           // == (bm%MAXINS)*9 + e4
    const int c  = batchidx[bm];
    float4 acc = selsrc[((size_t)bm * CAND + c) * CE4 + e4];
    const float4* p = partials + (size_t)b * BPB * BATCH_F4 + j;
    #pragma unroll 8
    for (int s = 0; s < BPB; ++s) {
        float4 v = p[(size_t)s * BATCH_F4];    // independent loads -> ILP
        acc.x += v.x; acc.y += v.y; acc.z += v.z; acc.w += v.w;
    }
    comp[t] = acc;
}

// ============ fallback (tiny ws): direct atomics =========================

__global__ void init_sel_kernel(const int* __restrict__ batchidx,
                                const float4* __restrict__ selsrc,
                                float4* __restrict__ comp) {
    unsigned t = blockIdx.x * blockDim.x + threadIdx.x;   // 7200
    if (t >= BZ * MAXINS * CE4) return;
    unsigned e4 = t % CE4;
    unsigned bm = t / CE4;
    int c = batchidx[bm];
    comp[bm * CE4 + e4] = selsrc[(bm * CAND + (unsigned)c) * CE4 + e4];
}

__global__ void compress_direct_kernel(const int* __restrict__ inst,
                                       const float4* __restrict__ compsrc,
                                       float* __restrict__ comp) {
    const unsigned total = BZ * PIX * CE4;
    for (unsigned t = blockIdx.x * blockDim.x + threadIdx.x; t < total;
         t += gridDim.x * blockDim.x) {
        unsigned e4 = t % CE4;
        unsigned pix = t / CE4;
        unsigned b = pix / PIX;
        int m = inst[pix];
        float4 v = compsrc[t];
        float* dst = comp + ((unsigned)(b * MAXINS + m)) * CE + e4 * 4;
        atomicAdd(dst + 0, v.x);
        atomicAdd(dst + 1, v.y);
        atomicAdd(dst + 2, v.z);
        atomicAdd(dst + 3, v.w);
    }
}

// ============ K3: inflate ================================================

__global__ void inflate_kernel(const int* __restrict__ inst,
                               const float4* __restrict__ comp,
                               float4* __restrict__ out) {
    const unsigned total = BZ * PIX * CE4;
    for (unsigned t = blockIdx.x * blockDim.x + threadIdx.x; t < total;
         t += gridDim.x * blockDim.x) {
        unsigned e4 = t % CE4;
        unsigned pix = t / CE4;
        unsigned b = pix / PIX;
        int m = inst[pix];
        out[t] = comp[((unsigned)(b * MAXINS + m)) * CE4 + e4];  // L2-hot gather
    }
}

extern "C" void kernel_launch(void* const* d_in, const int* in_sizes, int n_in,
                              void* d_out, int out_size, void* d_ws, size_t ws_size,
                              hipStream_t stream) {
    const int*    inst     = (const int*)d_in[0];      // (BZ,1,H,W) int32
    const float*  compsrc  = (const float*)d_in[1];    // (BZ,H,W,6,6) f32
    const int*    batchidx = (const int*)d_in[2];      // (BZ,MAXINS) int32
    const float*  selsrc   = (const float*)d_in[3];    // (BZ,MAXINS,CAND,6,6) f32
    float*        out      = (float*)d_out;            // (BZ,H,W,6,6) f32
    float*        comp     = (float*)d_ws;             // final comp: 115.2 KB @ ws[0]

    if (ws_size >= (size_t)COMP_BYTES + PART_BYTES) {
        // --- main path: counting-sort compress, no fp atomics, no zeroing ---
        float4* partials = (float4*)(comp + COMP_FLOATS);
        compress_sort_kernel<<<NBLK, TPB, 0, stream>>>(inst, (const float4*)compsrc,
                                                       partials);
        reduce_priv_kernel<<<(COMP_FLOATS / 4 + 255) / 256, 256, 0, stream>>>(
            partials, batchidx, (const float4*)selsrc, (float4*)comp);
    } else {
        // --- fallback: direct atomics into comp ---
        const int total = BZ * MAXINS * CE4;
        init_sel_kernel<<<(total + 255) / 256, 256, 0, stream>>>(
            batchidx, (const float4*)selsrc, (float4*)comp);
        compress_direct_kernel<<<2048, 256, 0, stream>>>(inst, (const float4*)compsrc,
                                                         comp);
    }

    // K3: inflate comp back to per-pixel output
    inflate_kernel<<<2048, 256, 0, stream>>>(inst, (const float4*)comp, (float4*)out);
}

// Round 16
// 54.030 us; speedup vs baseline: 1.1339x; 1.1339x over previous
//
#include <hip/hip_runtime.h>

// Problem constants (from reference setup_inputs)
#define BZ 4
#define H 192
#define W 640
#define PIX (H * W)            // 122880 pixels per batch
#define MAXINS 200
#define CAND 16
#define CE 36                  // ch*cw
#define CE4 9                  // float4 groups per pixel
#define BATCH_FLOATS (MAXINS * CE)          // 7200 floats per batch
#define BATCH_F4     (BATCH_FLOATS / 4)     // 1800 float4 per batch
#define COMP_FLOATS (BZ * BATCH_FLOATS)     // 28800 floats
#define COMP_BYTES  (COMP_FLOATS * 4)       // 115200 bytes
#define BPB 192                             // blocks per batch
#define NBLK (BZ * BPB)                     // 768 compress blocks
#define STRIPE (PIX / BPB)                  // 640 contiguous pixels per block
#define TPB 512                             // gather threads per block
#define ITEMS 4                             // ceil(1800/512) per-thread items
#define OFF_INTS (MAXINS + 1)
#define PART_BYTES ((size_t)NBLK * BATCH_FLOATS * 4)     // 22.1 MB
#define SORT_BYTES ((size_t)NBLK * STRIPE * 2)           // 983 KB (u16)
#define OFF_BYTES  ((size_t)NBLK * OFF_INTS * 4)         // 617 KB

// ============ K1a: sort (count + scan + scatter), writes sorted/off ======

__global__ __launch_bounds__(256) void sort_kernel(
        const int* __restrict__ inst,
        unsigned short* __restrict__ sortedbuf,
        int* __restrict__ offbuf) {
    __shared__ unsigned char  mloc[STRIPE];
    __shared__ unsigned short sorted[STRIPE];
    __shared__ int cnt[MAXINS];
    __shared__ int off_run[MAXINS];
    __shared__ int tmp[256];

    const int b    = blockIdx.x / BPB;
    const int blk  = blockIdx.x % BPB;
    const int tid  = threadIdx.x;
    const int pix0 = blk * STRIPE;

    if (tid < MAXINS) cnt[tid] = 0;
    __syncthreads();

    for (int p = tid; p < STRIPE; p += 256) {          // count
        int m = inst[b * PIX + pix0 + p];
        mloc[p] = (unsigned char)m;
        atomicAdd(&cnt[m], 1);
    }
    __syncthreads();

    int c = (tid < MAXINS) ? cnt[tid] : 0;             // Hillis-Steele scan
    tmp[tid] = c;
    __syncthreads();
    for (int s = 1; s < 256; s <<= 1) {
        int v = (tid >= s) ? tmp[tid - s] : 0;
        __syncthreads();
        tmp[tid] += v;
        __syncthreads();
    }
    if (tid < MAXINS) {
        off_run[tid] = tmp[tid] - c;
        offbuf[(size_t)blockIdx.x * OFF_INTS + tid] = tmp[tid] - c;
    }
    if (tid == 0) offbuf[(size_t)blockIdx.x * OFF_INTS + MAXINS] = STRIPE;
    __syncthreads();

    for (int p = tid; p < STRIPE; p += 256) {          // scatter
        int slot = atomicAdd(&off_run[mloc[p]], 1);
        sorted[slot] = (unsigned short)p;
    }
    __syncthreads();

    const unsigned* s32 = (const unsigned*)sorted;     // store sorted (u32 pairs)
    unsigned* dst = (unsigned*)(sortedbuf + (size_t)blockIdx.x * STRIPE);
    for (int i = tid; i < STRIPE / 2; i += 256) dst[i] = s32[i];
}

// ============ K1b: gather (r12-exact inner loop) ========================

__global__ __launch_bounds__(TPB) void gather_kernel(
        const unsigned short* __restrict__ sortedbuf,
        const int* __restrict__ offbuf,
        const float4* __restrict__ compsrc,
        float4* __restrict__ partials) {
    __shared__ unsigned short sorted[STRIPE];
    __shared__ int off[OFF_INTS];

    const int b    = blockIdx.x / BPB;
    const int blk  = blockIdx.x % BPB;
    const int tid  = threadIdx.x;
    const int pix0 = blk * STRIPE;

    {   // stage sorted + off into LDS
        const unsigned* s32 = (const unsigned*)(sortedbuf + (size_t)blockIdx.x * STRIPE);
        unsigned* d32 = (unsigned*)sorted;
        for (int i = tid; i < STRIPE / 2; i += TPB) d32[i] = s32[i];
        for (int i = tid; i < OFF_INTS; i += TPB)
            off[i] = offbuf[(size_t)blockIdx.x * OFF_INTS + i];
    }
    __syncthreads();

    // phase 2: per-(m,e4) register accumulation, batch-of-4 issue + prefetch
    const float4* src = compsrc + (size_t)(b * PIX + pix0) * CE4;
    float4 acc[ITEMS];
    int base_[ITEMS], len_[ITEMS], e4_[ITEMS], idx_[ITEMS];
    int maxlen = 0;
    #pragma unroll
    for (int j = 0; j < ITEMS; ++j) {
        const int item = tid + TPB * j;
        acc[j] = make_float4(0.f, 0.f, 0.f, 0.f);
        if (item < BATCH_F4) {
            const int m  = item / CE4;
            e4_[j]   = item - m * CE4;
            base_[j] = off[m];
            len_[j]  = off[m + 1] - off[m];
            maxlen   = len_[j] > maxlen ? len_[j] : maxlen;
        } else { base_[j] = 0; len_[j] = 0; e4_[j] = 0; }
        idx_[j] = (0 < len_[j]) ? (int)sorted[base_[j]] : 0;
    }
    for (int i = 0; i < maxlen; ++i) {
        float4 v[ITEMS];
        #pragma unroll
        for (int j = 0; j < ITEMS; ++j)
            if (i < len_[j]) v[j] = src[(size_t)idx_[j] * CE4 + e4_[j]];
        #pragma unroll
        for (int j = 0; j < ITEMS; ++j)
            idx_[j] = (i + 1 < len_[j]) ? (int)sorted[base_[j] + i + 1] : 0;
        #pragma unroll
        for (int j = 0; j < ITEMS; ++j)
            if (i < len_[j]) {
                acc[j].x += v[j].x; acc[j].y += v[j].y;
                acc[j].z += v[j].z; acc[j].w += v[j].w;
            }
    }

    float4* p = partials + (size_t)blockIdx.x * BATCH_F4;
    #pragma unroll
    for (int j = 0; j < ITEMS; ++j) {
        const int item = tid + TPB * j;
        if (item < BATCH_F4) p[item] = acc[j];
    }
}

// ============ K1-fused fallback (r12 kernel, if ws lacks sort/off room) ==

__global__ __launch_bounds__(TPB) void compress_sort_kernel(
        const int* __restrict__ inst,
        const float4* __restrict__ compsrc,
        float4* __restrict__ partials) {
    __shared__ unsigned char  mloc[STRIPE];
    __shared__ unsigned short sorted[STRIPE];
    __shared__ int cnt[MAXINS];
    __shared__ int off[OFF_INTS];
    __shared__ int off_run[MAXINS];
    __shared__ int tmp[TPB];

    const int b    = blockIdx.x / BPB;
    const int blk  = blockIdx.x % BPB;
    const int tid  = threadIdx.x;
    const int pix0 = blk * STRIPE;

    if (tid < MAXINS) cnt[tid] = 0;
    __syncthreads();
    for (int p = tid; p < STRIPE; p += TPB) {
        int m = inst[b * PIX + pix0 + p];
        mloc[p] = (unsigned char)m;
        atomicAdd(&cnt[m], 1);
    }
    __syncthreads();
    int c = (tid < MAXINS) ? cnt[tid] : 0;
    tmp[tid] = c;
    __syncthreads();
    for (int s = 1; s < TPB; s <<= 1) {
        int v = (tid >= s) ? tmp[tid - s] : 0;
        __syncthreads();
        tmp[tid] += v;
        __syncthreads();
    }
    if (tid < MAXINS) { off[tid] = tmp[tid] - c; off_run[tid] = tmp[tid] - c; }
    if (tid == 0) off[MAXINS] = STRIPE;
    __syncthreads();
    for (int p = tid; p < STRIPE; p += TPB) {
        int slot = atomicAdd(&off_run[mloc[p]], 1);
        sorted[slot] = (unsigned short)p;
    }
    __syncthreads();

    const float4* src = compsrc + (size_t)(b * PIX + pix0) * CE4;
    float4 acc[ITEMS];
    int base_[ITEMS], len_[ITEMS], e4_[ITEMS], idx_[ITEMS];
    int maxlen = 0;
    #pragma unroll
    for (int j = 0; j < ITEMS; ++j) {
        const int item = tid + TPB * j;
        acc[j] = make_float4(0.f, 0.f, 0.f, 0.f);
        if (item < BATCH_F4) {
            const int m  = item / CE4;
            e4_[j]   = item - m * CE4;
            base_[j] = off[m];
            len_[j]  = off[m + 1] - off[m];
            maxlen   = len_[j] > maxlen ? len_[j] : maxlen;
        } else { base_[j] = 0; len_[j] = 0; e4_[j] = 0; }
        idx_[j] = (0 < len_[j]) ? (int)sorted[base_[j]] : 0;
    }
    for (int i = 0; i < maxlen; ++i) {
        float4 v[ITEMS];
        #pragma unroll
        for (int j = 0; j < ITEMS; ++j)
            if (i < len_[j]) v[j] = src[(size_t)idx_[j] * CE4 + e4_[j]];
        #pragma unroll
        for (int j = 0; j < ITEMS; ++j)
            idx_[j] = (i + 1 < len_[j]) ? (int)sorted[base_[j] + i + 1] : 0;
        #pragma unroll
        for (int j = 0; j < ITEMS; ++j)
            if (i < len_[j]) {
                acc[j].x += v[j].x; acc[j].y += v[j].y;
                acc[j].z += v[j].z; acc[j].w += v[j].w;
            }
    }
    float4* p = partials + (size_t)blockIdx.x * BATCH_F4;
    #pragma unroll
    for (int j = 0; j < ITEMS; ++j) {
        const int item = tid + TPB * j;
        if (item < BATCH_F4) p[item] = acc[j];
    }
}

// ============ K2: reduce partials + sel gather ===========================

__global__ void reduce_priv_kernel(const float4* __restrict__ partials,
                                   const int* __restrict__ batchidx,
                                   const float4* __restrict__ selsrc,
                                   float4* __restrict__ comp) {
    const int t = blockIdx.x * blockDim.x + threadIdx.x;   // over 7200 float4
    if (t >= COMP_FLOATS / 4) return;
    const int e4 = t % CE4;
    const int bm = t / CE4;
    const int b  = t / BATCH_F4;
    const int j  = t - b * BATCH_F4;
    const int c  = batchidx[bm];
    float4 acc = selsrc[((size_t)bm * CAND + c) * CE4 + e4];
    const float4* p = partials + (size_t)b * BPB * BATCH_F4 + j;
    #pragma unroll 8
    for (int s = 0; s < BPB; ++s) {
        float4 v = p[(size_t)s * BATCH_F4];
        acc.x += v.x; acc.y += v.y; acc.z += v.z; acc.w += v.w;
    }
    comp[t] = acc;
}

// ============ fallback (tiny ws): direct atomics =========================

__global__ void init_sel_kernel(const int* __restrict__ batchidx,
                                const float4* __restrict__ selsrc,
                                float4* __restrict__ comp) {
    unsigned t = blockIdx.x * blockDim.x + threadIdx.x;
    if (t >= BZ * MAXINS * CE4) return;
    unsigned e4 = t % CE4;
    unsigned bm = t / CE4;
    int c = batchidx[bm];
    comp[bm * CE4 + e4] = selsrc[(bm * CAND + (unsigned)c) * CE4 + e4];
}

__global__ void compress_direct_kernel(const int* __restrict__ inst,
                                       const float4* __restrict__ compsrc,
                                       float* __restrict__ comp) {
    const unsigned total = BZ * PIX * CE4;
    for (unsigned t = blockIdx.x * blockDim.x + threadIdx.x; t < total;
         t += gridDim.x * blockDim.x) {
        unsigned e4 = t % CE4;
        unsigned pix = t / CE4;
        unsigned b = pix / PIX;
        int m = inst[pix];
        float4 v = compsrc[t];
        float* dst = comp + ((unsigned)(b * MAXINS + m)) * CE + e4 * 4;
        atomicAdd(dst + 0, v.x);
        atomicAdd(dst + 1, v.y);
        atomicAdd(dst + 2, v.z);
        atomicAdd(dst + 3, v.w);
    }
}

// ============ K3: inflate via LDS-cached comp slice ======================

__global__ __launch_bounds__(256) void inflate_lds_kernel(
        const int* __restrict__ inst,
        const float4* __restrict__ comp,
        float4* __restrict__ out) {
    __shared__ float4 lcomp[BATCH_F4];          // 28.8 KB: this batch's comp
    __shared__ unsigned char mloc[STRIPE];

    const int b    = blockIdx.x / BPB;
    const int blk  = blockIdx.x % BPB;
    const int tid  = threadIdx.x;
    const int pix0 = blk * STRIPE;

    for (int i = tid; i < BATCH_F4; i += 256)
        lcomp[i] = comp[(size_t)b * BATCH_F4 + i];
    for (int p = tid; p < STRIPE; p += 256)
        mloc[p] = (unsigned char)inst[b * PIX + pix0 + p];
    __syncthreads();

    const size_t base = (size_t)(b * PIX + pix0) * CE4;
    for (int t = tid; t < STRIPE * CE4; t += 256) {       // 5760 f4 / block
        const int pl = t / CE4;
        const int e4 = t - pl * CE4;
        out[base + t] = lcomp[(int)mloc[pl] * CE4 + e4];  // LDS read, coalesced store
    }
}

extern "C" void kernel_launch(void* const* d_in, const int* in_sizes, int n_in,
                              void* d_out, int out_size, void* d_ws, size_t ws_size,
                              hipStream_t stream) {
    const int*    inst     = (const int*)d_in[0];      // (BZ,1,H,W) int32
    const float*  compsrc  = (const float*)d_in[1];    // (BZ,H,W,6,6) f32
    const int*    batchidx = (const int*)d_in[2];      // (BZ,MAXINS) int32
    const float*  selsrc   = (const float*)d_in[3];    // (BZ,MAXINS,CAND,6,6) f32
    float*        out      = (float*)d_out;            // (BZ,H,W,6,6) f32
    float*        comp     = (float*)d_ws;             // 115.2 KB @ ws[0]

    const size_t need_fused = (size_t)COMP_BYTES + PART_BYTES;
    const size_t need_split = need_fused + SORT_BYTES + OFF_BYTES;

    if (ws_size >= need_split) {
        // --- split path: sort | gather (per-phase rocprof visibility) ---
        float4* partials = (float4*)(comp + COMP_FLOATS);
        unsigned short* sortedbuf =
            (unsigned short*)((char*)d_ws + need_fused);
        int* offbuf = (int*)((char*)d_ws + need_fused + SORT_BYTES);
        sort_kernel<<<NBLK, 256, 0, stream>>>(inst, sortedbuf, offbuf);
        gather_kernel<<<NBLK, TPB, 0, stream>>>(sortedbuf, offbuf,
                                                (const float4*)compsrc, partials);
        reduce_priv_kernel<<<(COMP_FLOATS / 4 + 255) / 256, 256, 0, stream>>>(
            partials, batchidx, (const float4*)selsrc, (float4*)comp);
    } else if (ws_size >= need_fused) {
        // --- fused r12 path ---
        float4* partials = (float4*)(comp + COMP_FLOATS);
        compress_sort_kernel<<<NBLK, TPB, 0, stream>>>(inst, (const float4*)compsrc,
                                                       partials);
        reduce_priv_kernel<<<(COMP_FLOATS / 4 + 255) / 256, 256, 0, stream>>>(
            partials, batchidx, (const float4*)selsrc, (float4*)comp);
    } else {
        // --- minimal-ws fallback: direct atomics ---
        const int total = BZ * MAXINS * CE4;
        init_sel_kernel<<<(total + 255) / 256, 256, 0, stream>>>(
            batchidx, (const float4*)selsrc, (float4*)comp);
        compress_direct_kernel<<<2048, 256, 0, stream>>>(inst, (const float4*)compsrc,
                                                         comp);
    }

    // K3: inflate via LDS-cached comp
    inflate_lds_kernel<<<NBLK, 256, 0, stream>>>(inst, (const float4*)comp,
                                                 (float4*)out);
}

// Round 18
// 53.313 us; speedup vs baseline: 1.1491x; 1.0134x over previous
//
#include <hip/hip_runtime.h>

// Problem constants (from reference setup_inputs)
#define BZ 4
#define H 192
#define W 640
#define PIX (H * W)            // 122880 pixels per batch
#define MAXINS 200
#define CAND 16
#define CE 36                  // ch*cw
#define CE4 9                  // float4 groups per pixel
#define BATCH_FLOATS (MAXINS * CE)          // 7200 floats per batch
#define BATCH_F4     (BATCH_FLOATS / 4)     // 1800 float4 per batch
#define COMP_FLOATS (BZ * BATCH_FLOATS)     // 28800 floats
#define COMP_BYTES  (COMP_FLOATS * 4)       // 115200 bytes
#define BPB 192                             // blocks per batch
#define NBLK (BZ * BPB)                     // 768 compress blocks
#define STRIPE (PIX / BPB)                  // 640 contiguous pixels per block
#define TPB 512                             // threads per block
#define ITEMS 4                             // items per thread (m-major)
#define PART_BYTES ((size_t)NBLK * BATCH_FLOATS * 4)   // 22.1 MB

// ============ compress: fused counting sort + m-major gather =============
// r12 (49.2us total) is the best-known base. Single change this round:
// item = tid*4+j (m-major) instead of tid+TPB*j. 4 consecutive items span
// <=2 distinct m -> per-thread lens ~equal -> masked-iteration waste
// (maxlen~5.5 vs avg 3.2) collapses; the 4 loads per iteration hit the
// same pixel's contiguous 64B.

__global__ __launch_bounds__(TPB) void compress_sort_kernel(
        const int* __restrict__ inst,
        const float4* __restrict__ compsrc,
        float4* __restrict__ partials) {
    __shared__ unsigned char  mloc[STRIPE];     // per-pixel m (cached)
    __shared__ unsigned short sorted[STRIPE];   // local pixel ids, grouped by m
    __shared__ int cnt[MAXINS];
    __shared__ int off[MAXINS + 1];
    __shared__ int off_run[MAXINS];
    __shared__ int tmp[TPB];

    const int b    = blockIdx.x / BPB;
    const int blk  = blockIdx.x % BPB;
    const int tid  = threadIdx.x;
    const int pix0 = blk * STRIPE;

    if (tid < MAXINS) cnt[tid] = 0;
    __syncthreads();

    // ---- count pass: 640 int LDS atomics, cache m ----
    for (int p = tid; p < STRIPE; p += TPB) {
        int m = inst[b * PIX + pix0 + p];       // coalesced
        mloc[p] = (unsigned char)m;
        atomicAdd(&cnt[m], 1);                  // ds_add_u32
    }
    __syncthreads();

    // ---- exclusive scan cnt -> off (Hillis-Steele, TPB-wide, uniform syncs) ----
    int c = (tid < MAXINS) ? cnt[tid] : 0;
    tmp[tid] = c;
    __syncthreads();
    for (int s = 1; s < TPB; s <<= 1) {
        int v = (tid >= s) ? tmp[tid - s] : 0;
        __syncthreads();
        tmp[tid] += v;
        __syncthreads();
    }
    if (tid < MAXINS) { off[tid] = tmp[tid] - c; off_run[tid] = tmp[tid] - c; }
    if (tid == 0) off[MAXINS] = STRIPE;
    __syncthreads();

    // ---- scatter local pixel ids into m-sorted order ----
    for (int p = tid; p < STRIPE; p += TPB) {
        int slot = atomicAdd(&off_run[mloc[p]], 1);   // ds_add_rtn_u32
        sorted[slot] = (unsigned short)p;
    }
    __syncthreads();

    // ---- phase 2: m-major register accumulation ----
    const float4* src = compsrc + (size_t)(b * PIX + pix0) * CE4;
    float4 acc[ITEMS];
    int base_[ITEMS], len_[ITEMS], e4_[ITEMS], idx_[ITEMS];
    int maxlen = 0;
    #pragma unroll
    for (int j = 0; j < ITEMS; ++j) {
        const int item = tid * ITEMS + j;       // m-major: <=2 distinct m/thread
        acc[j] = make_float4(0.f, 0.f, 0.f, 0.f);
        if (item < BATCH_F4) {
            const int m  = item / CE4;
            e4_[j]   = item - m * CE4;
            base_[j] = off[m];
            len_[j]  = off[m + 1] - off[m];
            maxlen   = len_[j] > maxlen ? len_[j] : maxlen;
        } else { base_[j] = 0; len_[j] = 0; e4_[j] = 0; }
        idx_[j] = (0 < len_[j]) ? (int)sorted[base_[j]] : 0;
    }
    for (int i = 0; i < maxlen; ++i) {
        float4 v[ITEMS];
        #pragma unroll
        for (int j = 0; j < ITEMS; ++j)         // 4 loads, same pixel, 64B contig
            if (i < len_[j]) v[j] = src[(size_t)idx_[j] * CE4 + e4_[j]];
        #pragma unroll
        for (int j = 0; j < ITEMS; ++j)         // LDS prefetch i+1
            idx_[j] = (i + 1 < len_[j]) ? (int)sorted[base_[j] + i + 1] : 0;
        #pragma unroll
        for (int j = 0; j < ITEMS; ++j)
            if (i < len_[j]) {
                acc[j].x += v[j].x; acc[j].y += v[j].y;
                acc[j].z += v[j].z; acc[j].w += v[j].w;
            }
    }

    // ---- store full partial: lane t writes 64B contiguous, wave-contiguous ----
    float4* p = partials + (size_t)blockIdx.x * BATCH_F4;
    #pragma unroll
    for (int j = 0; j < ITEMS; ++j) {
        const int item = tid * ITEMS + j;
        if (item < BATCH_F4) p[item] = acc[j];
    }
}

// ============ K2: reduce partials + sel gather ===========================

__global__ void reduce_priv_kernel(const float4* __restrict__ partials,
                                   const int* __restrict__ batchidx,
                                   const float4* __restrict__ selsrc,
                                   float4* __restrict__ comp) {
    const int t = blockIdx.x * blockDim.x + threadIdx.x;   // over 7200 float4
    if (t >= COMP_FLOATS / 4) return;
    const int e4 = t % CE4;
    const int bm = t / CE4;
    const int b  = t / BATCH_F4;
    const int j  = t - b * BATCH_F4;
    const int c  = batchidx[bm];
    float4 acc = selsrc[((size_t)bm * CAND + c) * CE4 + e4];
    const float4* p = partials + (size_t)b * BPB * BATCH_F4 + j;
    #pragma unroll 8
    for (int s = 0; s < BPB; ++s) {
        float4 v = p[(size_t)s * BATCH_F4];
        acc.x += v.x; acc.y += v.y; acc.z += v.z; acc.w += v.w;
    }
    comp[t] = acc;
}

// ============ fallback (tiny ws): direct atomics =========================

__global__ void init_sel_kernel(const int* __restrict__ batchidx,
                                const float4* __restrict__ selsrc,
                                float4* __restrict__ comp) {
    unsigned t = blockIdx.x * blockDim.x + threadIdx.x;
    if (t >= BZ * MAXINS * CE4) return;
    unsigned e4 = t % CE4;
    unsigned bm = t / CE4;
    int c = batchidx[bm];
    comp[bm * CE4 + e4] = selsrc[(bm * CAND + (unsigned)c) * CE4 + e4];
}

__global__ void compress_direct_kernel(const int* __restrict__ inst,
                                       const float4* __restrict__ compsrc,
                                       float* __restrict__ comp) {
    const unsigned total = BZ * PIX * CE4;
    for (unsigned t = blockIdx.x * blockDim.x + threadIdx.x; t < total;
         t += gridDim.x * blockDim.x) {
        unsigned e4 = t % CE4;
        unsigned pix = t / CE4;
        unsigned b = pix / PIX;
        int m = inst[pix];
        float4 v = compsrc[t];
        float* dst = comp + ((unsigned)(b * MAXINS + m)) * CE + e4 * 4;
        atomicAdd(dst + 0, v.x);
        atomicAdd(dst + 1, v.y);
        atomicAdd(dst + 2, v.z);
        atomicAdd(dst + 3, v.w);
    }
}

// ============ K3: inflate (r12 global-gather variant, known 15.5us) ======

__global__ void inflate_kernel(const int* __restrict__ inst,
                               const float4* __restrict__ comp,
                               float4* __restrict__ out) {
    const unsigned total = BZ * PIX * CE4;
    for (unsigned t = blockIdx.x * blockDim.x + threadIdx.x; t < total;
         t += gridDim.x * blockDim.x) {
        unsigned e4 = t % CE4;
        unsigned pix = t / CE4;
        unsigned b = pix / PIX;
        int m = inst[pix];
        out[t] = comp[((unsigned)(b * MAXINS + m)) * CE4 + e4];  // L2-hot gather
    }
}

extern "C" void kernel_launch(void* const* d_in, const int* in_sizes, int n_in,
                              void* d_out, int out_size, void* d_ws, size_t ws_size,
                              hipStream_t stream) {
    const int*    inst     = (const int*)d_in[0];      // (BZ,1,H,W) int32
    const float*  compsrc  = (const float*)d_in[1];    // (BZ,H,W,6,6) f32
    const int*    batchidx = (const int*)d_in[2];      // (BZ,MAXINS) int32
    const float*  selsrc   = (const float*)d_in[3];    // (BZ,MAXINS,CAND,6,6) f32
    float*        out      = (float*)d_out;            // (BZ,H,W,6,6) f32
    float*        comp     = (float*)d_ws;             // 115.2 KB @ ws[0]

    if (ws_size >= (size_t)COMP_BYTES + PART_BYTES) {
        // --- main path: fused counting-sort compress (m-major gather) ---
        float4* partials = (float4*)(comp + COMP_FLOATS);
        compress_sort_kernel<<<NBLK, TPB, 0, stream>>>(inst, (const float4*)compsrc,
                                                       partials);
        reduce_priv_kernel<<<(COMP_FLOATS / 4 + 255) / 256, 256, 0, stream>>>(
            partials, batchidx, (const float4*)selsrc, (float4*)comp);
    } else {
        // --- fallback: direct atomics into comp ---
        const int total = BZ * MAXINS * CE4;
        init_sel_kernel<<<(total + 255) / 256, 256, 0, stream>>>(
            batchidx, (const float4*)selsrc, (float4*)comp);
        compress_direct_kernel<<<2048, 256, 0, stream>>>(inst, (const float4*)compsrc,
                                                         comp);
    }

    // K3: inflate comp back to per-pixel output
    inflate_kernel<<<2048, 256, 0, stream>>>(inst, (const float4*)comp, (float4*)out);
}

// Round 19
// 51.546 us; speedup vs baseline: 1.1885x; 1.0343x over previous
//
#include <hip/hip_runtime.h>

// Problem constants (from reference setup_inputs)
#define BZ 4
#define H 192
#define W 640
#define PIX (H * W)            // 122880 pixels per batch
#define MAXINS 200
#define CAND 16
#define CE 36                  // ch*cw
#define CE4 9                  // float4 groups per pixel
#define BATCH_FLOATS (MAXINS * CE)          // 7200 floats per batch
#define BATCH_F4     (BATCH_FLOATS / 4)     // 1800 float4 per batch
#define COMP_FLOATS (BZ * BATCH_FLOATS)     // 28800 floats
#define COMP_BYTES  (COMP_FLOATS * 4)       // 115200 bytes
#define BPB 192                             // blocks per batch
#define NBLK (BZ * BPB)                     // 768 compress blocks
#define STRIPE (PIX / BPB)                  // 640 contiguous pixels per block
#define HALF 320                            // pixels staged in LDS at a time
#define TPB 512                             // threads per block
#define ITEMS 4                             // items per thread (item-major, r12)
#define PART_BYTES ((size_t)NBLK * BATCH_FLOATS * 4)   // 22.1 MB

// ============ compress: counting sort + LDS-staged gather ================
// r12/r15/r18 localized the wall: random 144B gather reads from L2 (~300cyc)
// can't be latency-hidden. Fix: stage each 320-pixel half-stripe into LDS
// with coalesced streaming reads, then gather from LDS (~120cyc, banked).

__global__ __launch_bounds__(TPB) void compress_sort_kernel(
        const int* __restrict__ inst,
        const float4* __restrict__ compsrc,
        float4* __restrict__ partials) {
    __shared__ float4 ldata[HALF * CE4];        // 45 KB: half-stripe pixel data
    __shared__ unsigned char  mloc[HALF];
    __shared__ unsigned short sorted[HALF];     // half-local pixel ids by m
    __shared__ int cnt[MAXINS];
    __shared__ int off[MAXINS + 1];
    __shared__ int off_run[MAXINS];
    __shared__ int tmp[256];

    const int b    = blockIdx.x / BPB;
    const int blk  = blockIdx.x % BPB;
    const int tid  = threadIdx.x;
    const int pix0 = blk * STRIPE;

    // item decomposition fixed across halves (r12 item-major layout)
    float4 acc[ITEMS];
    int e4_[ITEMS], m_[ITEMS];
    #pragma unroll
    for (int j = 0; j < ITEMS; ++j) {
        const int item = tid + TPB * j;
        acc[j] = make_float4(0.f, 0.f, 0.f, 0.f);
        if (item < BATCH_F4) { m_[j] = item / CE4; e4_[j] = item - m_[j] * CE4; }
        else                 { m_[j] = 0;          e4_[j] = 0; }
    }
    const bool live0 = (tid < BATCH_F4);        // item j live iff j==0 check below

    for (int h = 0; h < 2; ++h) {
        const int pixh = pix0 + h * HALF;

        // ---- stage half-stripe into LDS (fully coalesced) ----
        const float4* srch = compsrc + (size_t)(b * PIX + pixh) * CE4;
        for (int i = tid; i < HALF * CE4; i += TPB) ldata[i] = srch[i];

        if (tid < MAXINS) cnt[tid] = 0;
        __syncthreads();

        // ---- count + cache m ----
        for (int p = tid; p < HALF; p += TPB) {
            int m = inst[b * PIX + pixh + p];
            mloc[p] = (unsigned char)m;
            atomicAdd(&cnt[m], 1);
        }
        __syncthreads();

        // ---- exclusive scan over 256 slots (8 rounds) ----
        int c = (tid < MAXINS) ? cnt[tid] : 0;
        if (tid < 256) tmp[tid] = c;
        __syncthreads();
        for (int s = 1; s < 256; s <<= 1) {
            int v = (tid >= s && tid < 256) ? tmp[tid - s] : 0;
            __syncthreads();
            if (tid < 256) tmp[tid] += v;
            __syncthreads();
        }
        if (tid < MAXINS) { off[tid] = tmp[tid] - c; off_run[tid] = tmp[tid] - c; }
        if (tid == 0) off[MAXINS] = HALF;
        __syncthreads();

        // ---- scatter half-local pixel ids ----
        for (int p = tid; p < HALF; p += TPB) {
            int slot = atomicAdd(&off_run[mloc[p]], 1);
            sorted[slot] = (unsigned short)p;
        }
        __syncthreads();

        // ---- gather from LDS (r12-exact loop, ds_read instead of global) ----
        int base_[ITEMS], len_[ITEMS], idx_[ITEMS];
        int maxlen = 0;
        #pragma unroll
        for (int j = 0; j < ITEMS; ++j) {
            const bool live = (j == 0) ? live0 : true;  // items 1..3 always < 1800
            if (live) {
                base_[j] = off[m_[j]];
                len_[j]  = off[m_[j] + 1] - base_[j];
                maxlen   = len_[j] > maxlen ? len_[j] : maxlen;
            } else { base_[j] = 0; len_[j] = 0; }
            idx_[j] = (0 < len_[j]) ? (int)sorted[base_[j]] : 0;
        }
        for (int i = 0; i < maxlen; ++i) {
            float4 v[ITEMS];
            #pragma unroll
            for (int j = 0; j < ITEMS; ++j)
                if (i < len_[j]) v[j] = ldata[idx_[j] * CE4 + e4_[j]];  // ds_read_b128
            #pragma unroll
            for (int j = 0; j < ITEMS; ++j)
                idx_[j] = (i + 1 < len_[j]) ? (int)sorted[base_[j] + i + 1] : 0;
            #pragma unroll
            for (int j = 0; j < ITEMS; ++j)
                if (i < len_[j]) {
                    acc[j].x += v[j].x; acc[j].y += v[j].y;
                    acc[j].z += v[j].z; acc[j].w += v[j].w;
                }
        }
        __syncthreads();   // before next half overwrites ldata/sorted
    }

    // ---- store full partial (zeros included): every byte overwritten ----
    float4* p = partials + (size_t)blockIdx.x * BATCH_F4;
    #pragma unroll
    for (int j = 0; j < ITEMS; ++j) {
        const int item = tid + TPB * j;
        if (item < BATCH_F4) p[item] = acc[j];
    }
}

// ============ K2: reduce partials + sel gather ===========================

__global__ void reduce_priv_kernel(const float4* __restrict__ partials,
                                   const int* __restrict__ batchidx,
                                   const float4* __restrict__ selsrc,
                                   float4* __restrict__ comp) {
    const int t = blockIdx.x * blockDim.x + threadIdx.x;   // over 7200 float4
    if (t >= COMP_FLOATS / 4) return;
    const int e4 = t % CE4;
    const int bm = t / CE4;
    const int b  = t / BATCH_F4;
    const int j  = t - b * BATCH_F4;
    const int c  = batchidx[bm];
    float4 acc = selsrc[((size_t)bm * CAND + c) * CE4 + e4];
    const float4* p = partials + (size_t)b * BPB * BATCH_F4 + j;
    #pragma unroll 8
    for (int s = 0; s < BPB; ++s) {
        float4 v = p[(size_t)s * BATCH_F4];
        acc.x += v.x; acc.y += v.y; acc.z += v.z; acc.w += v.w;
    }
    comp[t] = acc;
}

// ============ fallback (tiny ws): direct atomics =========================

__global__ void init_sel_kernel(const int* __restrict__ batchidx,
                                const float4* __restrict__ selsrc,
                                float4* __restrict__ comp) {
    unsigned t = blockIdx.x * blockDim.x + threadIdx.x;
    if (t >= BZ * MAXINS * CE4) return;
    unsigned e4 = t % CE4;
    unsigned bm = t / CE4;
    int c = batchidx[bm];
    comp[bm * CE4 + e4] = selsrc[(bm * CAND + (unsigned)c) * CE4 + e4];
}

__global__ void compress_direct_kernel(const int* __restrict__ inst,
                                       const float4* __restrict__ compsrc,
                                       float* __restrict__ comp) {
    const unsigned total = BZ * PIX * CE4;
    for (unsigned t = blockIdx.x * blockDim.x + threadIdx.x; t < total;
         t += gridDim.x * blockDim.x) {
        unsigned e4 = t % CE4;
        unsigned pix = t / CE4;
        unsigned b = pix / PIX;
        int m = inst[pix];
        float4 v = compsrc[t];
        float* dst = comp + ((unsigned)(b * MAXINS + m)) * CE + e4 * 4;
        atomicAdd(dst + 0, v.x);
        atomicAdd(dst + 1, v.y);
        atomicAdd(dst + 2, v.z);
        atomicAdd(dst + 3, v.w);
    }
}

// ============ K3: inflate ================================================

__global__ void inflate_kernel(const int* __restrict__ inst,
                               const float4* __restrict__ comp,
                               float4* __restrict__ out) {
    const unsigned total = BZ * PIX * CE4;
    for (unsigned t = blockIdx.x * blockDim.x + threadIdx.x; t < total;
         t += gridDim.x * blockDim.x) {
        unsigned e4 = t % CE4;
        unsigned pix = t / CE4;
        unsigned b = pix / PIX;
        int m = inst[pix];
        out[t] = comp[((unsigned)(b * MAXINS + m)) * CE4 + e4];  // L2-hot gather
    }
}

extern "C" void kernel_launch(void* const* d_in, const int* in_sizes, int n_in,
                              void* d_out, int out_size, void* d_ws, size_t ws_size,
                              hipStream_t stream) {
    const int*    inst     = (const int*)d_in[0];      // (BZ,1,H,W) int32
    const float*  compsrc  = (const float*)d_in[1];    // (BZ,H,W,6,6) f32
    const int*    batchidx = (const int*)d_in[2];      // (BZ,MAXINS) int32
    const float*  selsrc   = (const float*)d_in[3];    // (BZ,MAXINS,CAND,6,6) f32
    float*        out      = (float*)d_out;            // (BZ,H,W,6,6) f32
    float*        comp     = (float*)d_ws;             // 115.2 KB @ ws[0]

    if (ws_size >= (size_t)COMP_BYTES + PART_BYTES) {
        // --- main path: LDS-staged counting-sort compress ---
        float4* partials = (float4*)(comp + COMP_FLOATS);
        compress_sort_kernel<<<NBLK, TPB, 0, stream>>>(inst, (const float4*)compsrc,
                                                       partials);
        reduce_priv_kernel<<<(COMP_FLOATS / 4 + 255) / 256, 256, 0, stream>>>(
            partials, batchidx, (const float4*)selsrc, (float4*)comp);
    } else {
        // --- fallback: direct atomics into comp ---
        const int total = BZ * MAXINS * CE4;
        init_sel_kernel<<<(total + 255) / 256, 256, 0, stream>>>(
            batchidx, (const float4*)selsrc, (float4*)comp);
        compress_direct_kernel<<<2048, 256, 0, stream>>>(inst, (const float4*)compsrc,
                                                         comp);
    }

    // K3: inflate comp back to per-pixel output
    inflate_kernel<<<2048, 256, 0, stream>>>(inst, (const float4*)comp, (float4*)out);
}

// Round 20
// 49.420 us; speedup vs baseline: 1.2397x; 1.0430x over previous
//
#include <hip/hip_runtime.h>

// Problem constants (from reference setup_inputs)
#define BZ 4
#define H 192
#define W 640
#define PIX (H * W)            // 122880 pixels per batch
#define MAXINS 200
#define CAND 16
#define CE 36                  // ch*cw
#define CE4 9                  // float4 groups per pixel
#define BATCH_FLOATS (MAXINS * CE)          // 7200 floats per batch
#define BATCH_F4     (BATCH_FLOATS / 4)     // 1800 float4 per batch
#define COMP_FLOATS (BZ * BATCH_FLOATS)     // 28800 floats
#define COMP_BYTES  (COMP_FLOATS * 4)       // 115200 bytes
#define BPB 192                             // blocks per batch
#define NBLK (BZ * BPB)                     // 768 compress blocks
#define STRIPE (PIX / BPB)                  // 640 contiguous pixels per block
#define TPB 512                             // threads per block
#define PART_BYTES ((size_t)NBLK * BATCH_FLOATS * 4)   // 22.1 MB

// ============ compress: counting sort + per-m whole-pixel streaming ======
// r12/r15/r18/r19 localized the wall to the gather's SERIAL ROUND structure
// (~5.5 masked rounds x 4-deep loads). New decomposition: thread pair
// (2m,2m+1) owns instance m; each reads whole pixels (9 contiguous f4 =
// 9-deep MLP free), ~2 rounds; pair-reduce via shfl_xor(1); coalesced
// item-major store via one LDS staging pass.

__global__ __launch_bounds__(TPB) void compress_sort_kernel(
        const int* __restrict__ inst,
        const float4* __restrict__ compsrc,
        float4* __restrict__ partials) {
    __shared__ unsigned char  mloc[STRIPE];
    __shared__ unsigned short sorted[STRIPE];   // pixel ids grouped by m
    __shared__ int cnt[MAXINS];
    __shared__ int off[MAXINS + 1];
    __shared__ int off_run[MAXINS];
    __shared__ int tmp[256];
    __shared__ float4 xbuf[BATCH_F4];           // 28.8 KB: final per-m sums

    const int b    = blockIdx.x / BPB;
    const int blk  = blockIdx.x % BPB;
    const int tid  = threadIdx.x;
    const int pix0 = blk * STRIPE;

    if (tid < MAXINS) cnt[tid] = 0;
    __syncthreads();

    // ---- count pass: cache m, 640 int LDS atomics ----
    for (int p = tid; p < STRIPE; p += TPB) {
        int m = inst[b * PIX + pix0 + p];       // coalesced
        mloc[p] = (unsigned char)m;
        atomicAdd(&cnt[m], 1);                  // ds_add_u32
    }
    __syncthreads();

    // ---- exclusive scan over 256 slots (8 rounds, uniform syncs) ----
    int c = (tid < MAXINS) ? cnt[tid] : 0;
    if (tid < 256) tmp[tid] = c;
    __syncthreads();
    for (int s = 1; s < 256; s <<= 1) {
        int v = (tid >= s && tid < 256) ? tmp[tid - s] : 0;
        __syncthreads();
        if (tid < 256) tmp[tid] += v;
        __syncthreads();
    }
    if (tid < MAXINS) { off[tid] = tmp[tid] - c; off_run[tid] = tmp[tid] - c; }
    if (tid == 0) off[MAXINS] = STRIPE;
    __syncthreads();

    // ---- scatter pixel ids into m-sorted order ----
    for (int p = tid; p < STRIPE; p += TPB) {
        int slot = atomicAdd(&off_run[mloc[p]], 1);   // ds_add_rtn_u32
        sorted[slot] = (unsigned short)p;
    }
    __syncthreads();

    // ---- per-m whole-pixel accumulation (threads 0..399, pair per m) ----
    const float4* src = compsrc + (size_t)(b * PIX + pix0) * CE4;
    float4 acc[CE4];
    #pragma unroll
    for (int k = 0; k < CE4; ++k) acc[k] = make_float4(0.f, 0.f, 0.f, 0.f);

    if (tid < 2 * MAXINS) {
        const int m      = tid >> 1;
        const int parity = tid & 1;
        const int base   = off[m];
        const int len    = off[m + 1] - base;
        for (int s = parity; s < len; s += 2) {
            const float4* q = src + (size_t)sorted[base + s] * CE4;
            #pragma unroll
            for (int k = 0; k < CE4; ++k) {     // 9 independent contiguous loads
                float4 v = q[k];
                acc[k].x += v.x; acc[k].y += v.y;
                acc[k].z += v.z; acc[k].w += v.w;
            }
        }
    }

    // ---- pair reduction: lane 2m += lane 2m+1 (same wave, adjacent) ----
    #pragma unroll
    for (int k = 0; k < CE4; ++k) {
        acc[k].x += __shfl_xor(acc[k].x, 1);
        acc[k].y += __shfl_xor(acc[k].y, 1);
        acc[k].z += __shfl_xor(acc[k].z, 1);
        acc[k].w += __shfl_xor(acc[k].w, 1);
    }
    if (tid < 2 * MAXINS && (tid & 1) == 0) {
        const int m = tid >> 1;
        #pragma unroll
        for (int k = 0; k < CE4; ++k) xbuf[m * CE4 + k] = acc[k];
    }
    __syncthreads();

    // ---- coalesced item-major store of the full partial ----
    float4* p = partials + (size_t)blockIdx.x * BATCH_F4;
    #pragma unroll
    for (int j = 0; j < 4; ++j) {
        const int item = tid + TPB * j;
        if (item < BATCH_F4) p[item] = xbuf[item];
    }
}

// ============ K2: reduce partials + sel gather ===========================

__global__ void reduce_priv_kernel(const float4* __restrict__ partials,
                                   const int* __restrict__ batchidx,
                                   const float4* __restrict__ selsrc,
                                   float4* __restrict__ comp) {
    const int t = blockIdx.x * blockDim.x + threadIdx.x;   // over 7200 float4
    if (t >= COMP_FLOATS / 4) return;
    const int e4 = t % CE4;
    const int bm = t / CE4;
    const int b  = t / BATCH_F4;
    const int j  = t - b * BATCH_F4;
    const int c  = batchidx[bm];
    float4 acc = selsrc[((size_t)bm * CAND + c) * CE4 + e4];
    const float4* p = partials + (size_t)b * BPB * BATCH_F4 + j;
    #pragma unroll 8
    for (int s = 0; s < BPB; ++s) {
        float4 v = p[(size_t)s * BATCH_F4];
        acc.x += v.x; acc.y += v.y; acc.z += v.z; acc.w += v.w;
    }
    comp[t] = acc;
}

// ============ fallback (tiny ws): direct atomics =========================

__global__ void init_sel_kernel(const int* __restrict__ batchidx,
                                const float4* __restrict__ selsrc,
                                float4* __restrict__ comp) {
    unsigned t = blockIdx.x * blockDim.x + threadIdx.x;
    if (t >= BZ * MAXINS * CE4) return;
    unsigned e4 = t % CE4;
    unsigned bm = t / CE4;
    int c = batchidx[bm];
    comp[bm * CE4 + e4] = selsrc[(bm * CAND + (unsigned)c) * CE4 + e4];
}

__global__ void compress_direct_kernel(const int* __restrict__ inst,
                                       const float4* __restrict__ compsrc,
                                       float* __restrict__ comp) {
    const unsigned total = BZ * PIX * CE4;
    for (unsigned t = blockIdx.x * blockDim.x + threadIdx.x; t < total;
         t += gridDim.x * blockDim.x) {
        unsigned e4 = t % CE4;
        unsigned pix = t / CE4;
        unsigned b = pix / PIX;
        int m = inst[pix];
        float4 v = compsrc[t];
        float* dst = comp + ((unsigned)(b * MAXINS + m)) * CE + e4 * 4;
        atomicAdd(dst + 0, v.x);
        atomicAdd(dst + 1, v.y);
        atomicAdd(dst + 2, v.z);
        atomicAdd(dst + 3, v.w);
    }
}

// ============ K3: inflate ================================================

__global__ void inflate_kernel(const int* __restrict__ inst,
                               const float4* __restrict__ comp,
                               float4* __restrict__ out) {
    const unsigned total = BZ * PIX * CE4;
    for (unsigned t = blockIdx.x * blockDim.x + threadIdx.x; t < total;
         t += gridDim.x * blockDim.x) {
        unsigned e4 = t % CE4;
        unsigned pix = t / CE4;
        unsigned b = pix / PIX;
        int m = inst[pix];
        out[t] = comp[((unsigned)(b * MAXINS + m)) * CE4 + e4];  // L2-hot gather
    }
}

extern "C" void kernel_launch(void* const* d_in, const int* in_sizes, int n_in,
                              void* d_out, int out_size, void* d_ws, size_t ws_size,
                              hipStream_t stream) {
    const int*    inst     = (const int*)d_in[0];      // (BZ,1,H,W) int32
    const float*  compsrc  = (const float*)d_in[1];    // (BZ,H,W,6,6) f32
    const int*    batchidx = (const int*)d_in[2];      // (BZ,MAXINS) int32
    const float*  selsrc   = (const float*)d_in[3];    // (BZ,MAXINS,CAND,6,6) f32
    float*        out      = (float*)d_out;            // (BZ,H,W,6,6) f32
    float*        comp     = (float*)d_ws;             // 115.2 KB @ ws[0]

    if (ws_size >= (size_t)COMP_BYTES + PART_BYTES) {
        // --- main path: counting-sort + per-m streaming compress ---
        float4* partials = (float4*)(comp + COMP_FLOATS);
        compress_sort_kernel<<<NBLK, TPB, 0, stream>>>(inst, (const float4*)compsrc,
                                                       partials);
        reduce_priv_kernel<<<(COMP_FLOATS / 4 + 255) / 256, 256, 0, stream>>>(
            partials, batchidx, (const float4*)selsrc, (float4*)comp);
    } else {
        // --- fallback: direct atomics into comp ---
        const int total = BZ * MAXINS * CE4;
        init_sel_kernel<<<(total + 255) / 256, 256, 0, stream>>>(
            batchidx, (const float4*)selsrc, (float4*)comp);
        compress_direct_kernel<<<2048, 256, 0, stream>>>(inst, (const float4*)compsrc,
                                                         comp);
    }

    // K3: inflate comp back to per-pixel output
    inflate_kernel<<<2048, 256, 0, stream>>>(inst, (const float4*)comp, (float4*)out);
}

// Round 21
// 49.141 us; speedup vs baseline: 1.2467x; 1.0057x over previous
//
#include <hip/hip_runtime.h>

// Problem constants (from reference setup_inputs)
#define BZ 4
#define H 192
#define W 640
#define PIX (H * W)            // 122880 pixels per batch
#define MAXINS 200
#define CAND 16
#define CE 36                  // ch*cw
#define CE4 9                  // float4 groups per pixel
#define BATCH_FLOATS (MAXINS * CE)          // 7200 floats per batch
#define BATCH_F4     (BATCH_FLOATS / 4)     // 1800 float4 per batch
#define COMP_FLOATS (BZ * BATCH_FLOATS)     // 28800 floats
#define COMP_BYTES  (COMP_FLOATS * 4)       // 115200 bytes
#define BPB 192                             // blocks per batch
#define NBLK (BZ * BPB)                     // 768 compress blocks
#define STRIPE (PIX / BPB)                  // 640 contiguous pixels per block
#define TPB 512                             // threads per block
#define ITEMS 4                             // items per thread (item-major, r12)
#define PART_BYTES ((size_t)NBLK * BATCH_FLOATS * 4)   // 22.1 MB

// ============ compress: barrier-light counting sort + r12 gather =========
// r12/r15/r18/r19/r20: five gather structures all ~28-30us -> gather loop
// is NOT the binder. Common cost: ~20 block-wide barriers (16 from the
// Hillis-Steele scan). This round: single-wave shfl scan (0 barriers) ->
// 4 barriers total. Gather is r12-exact.

__global__ __launch_bounds__(TPB) void compress_sort_kernel(
        const int* __restrict__ inst,
        const float4* __restrict__ compsrc,
        float4* __restrict__ partials) {
    __shared__ unsigned char  mloc[STRIPE];     // per-pixel m (cached)
    __shared__ unsigned short sorted[STRIPE];   // local pixel ids, grouped by m
    __shared__ int cnt[MAXINS];
    __shared__ int off[MAXINS + 1];
    __shared__ int off_run[MAXINS];

    const int b    = blockIdx.x / BPB;
    const int blk  = blockIdx.x % BPB;
    const int tid  = threadIdx.x;
    const int pix0 = blk * STRIPE;

    if (tid < MAXINS) cnt[tid] = 0;
    __syncthreads();                             // barrier 1

    // ---- count pass: 640 int LDS atomics, cache m ----
    for (int p = tid; p < STRIPE; p += TPB) {
        int m = inst[b * PIX + pix0 + p];        // coalesced
        mloc[p] = (unsigned char)m;
        atomicAdd(&cnt[m], 1);                   // ds_add_u32
    }
    __syncthreads();                             // barrier 2

    // ---- single-wave exclusive scan (wave 0, shfl, no barriers) ----
    if (tid < 64) {
        const int lane = tid;
        int run = 0;
        #pragma unroll
        for (int c = 0; c < 4; ++c) {            // 4 chunks of 64 bins
            const int idx = c * 64 + lane;       // 0..255
            int v = (idx < MAXINS) ? cnt[idx] : 0;
            const int own = v;
            #pragma unroll
            for (int s = 1; s < 64; s <<= 1) {   // inclusive wave scan
                int u = __shfl_up(v, s);
                if (lane >= s) v += u;
            }
            const int excl = run + v - own;
            if (idx < MAXINS) { off[idx] = excl; off_run[idx] = excl; }
            run += __shfl(v, 63);                // chunk total
        }
        if (lane == 0) off[MAXINS] = STRIPE;
    }
    __syncthreads();                             // barrier 3

    // ---- scatter local pixel ids into m-sorted order ----
    for (int p = tid; p < STRIPE; p += TPB) {
        int slot = atomicAdd(&off_run[mloc[p]], 1);   // ds_add_rtn_u32
        sorted[slot] = (unsigned short)p;
    }
    __syncthreads();                             // barrier 4

    // ---- phase 2: r12-exact item-major register accumulation ----
    const float4* src = compsrc + (size_t)(b * PIX + pix0) * CE4;
    float4 acc[ITEMS];
    int base_[ITEMS], len_[ITEMS], e4_[ITEMS], idx_[ITEMS];
    int maxlen = 0;
    #pragma unroll
    for (int j = 0; j < ITEMS; ++j) {
        const int item = tid + TPB * j;
        acc[j] = make_float4(0.f, 0.f, 0.f, 0.f);
        if (item < BATCH_F4) {
            const int m  = item / CE4;
            e4_[j]   = item - m * CE4;
            base_[j] = off[m];
            len_[j]  = off[m + 1] - off[m];
            maxlen   = len_[j] > maxlen ? len_[j] : maxlen;
        } else { base_[j] = 0; len_[j] = 0; e4_[j] = 0; }
        idx_[j] = (0 < len_[j]) ? (int)sorted[base_[j]] : 0;
    }
    for (int i = 0; i < maxlen; ++i) {
        float4 v[ITEMS];
        #pragma unroll
        for (int j = 0; j < ITEMS; ++j)
            if (i < len_[j]) v[j] = src[(size_t)idx_[j] * CE4 + e4_[j]];
        #pragma unroll
        for (int j = 0; j < ITEMS; ++j)
            idx_[j] = (i + 1 < len_[j]) ? (int)sorted[base_[j] + i + 1] : 0;
        #pragma unroll
        for (int j = 0; j < ITEMS; ++j)
            if (i < len_[j]) {
                acc[j].x += v[j].x; acc[j].y += v[j].y;
                acc[j].z += v[j].z; acc[j].w += v[j].w;
            }
    }

    // ---- store full partial (zeros included): every byte overwritten ----
    float4* p = partials + (size_t)blockIdx.x * BATCH_F4;
    #pragma unroll
    for (int j = 0; j < ITEMS; ++j) {
        const int item = tid + TPB * j;
        if (item < BATCH_F4) p[item] = acc[j];
    }
}

// ============ K2: reduce partials + sel gather ===========================

__global__ void reduce_priv_kernel(const float4* __restrict__ partials,
                                   const int* __restrict__ batchidx,
                                   const float4* __restrict__ selsrc,
                                   float4* __restrict__ comp) {
    const int t = blockIdx.x * blockDim.x + threadIdx.x;   // over 7200 float4
    if (t >= COMP_FLOATS / 4) return;
    const int e4 = t % CE4;
    const int bm = t / CE4;
    const int b  = t / BATCH_F4;
    const int j  = t - b * BATCH_F4;
    const int c  = batchidx[bm];
    float4 acc = selsrc[((size_t)bm * CAND + c) * CE4 + e4];
    const float4* p = partials + (size_t)b * BPB * BATCH_F4 + j;
    #pragma unroll 8
    for (int s = 0; s < BPB; ++s) {
        float4 v = p[(size_t)s * BATCH_F4];
        acc.x += v.x; acc.y += v.y; acc.z += v.z; acc.w += v.w;
    }
    comp[t] = acc;
}

// ============ fallback (tiny ws): direct atomics =========================

__global__ void init_sel_kernel(const int* __restrict__ batchidx,
                                const float4* __restrict__ selsrc,
                                float4* __restrict__ comp) {
    unsigned t = blockIdx.x * blockDim.x + threadIdx.x;
    if (t >= BZ * MAXINS * CE4) return;
    unsigned e4 = t % CE4;
    unsigned bm = t / CE4;
    int c = batchidx[bm];
    comp[bm * CE4 + e4] = selsrc[(bm * CAND + (unsigned)c) * CE4 + e4];
}

__global__ void compress_direct_kernel(const int* __restrict__ inst,
                                       const float4* __restrict__ compsrc,
                                       float* __restrict__ comp) {
    const unsigned total = BZ * PIX * CE4;
    for (unsigned t = blockIdx.x * blockDim.x + threadIdx.x; t < total;
         t += gridDim.x * blockDim.x) {
        unsigned e4 = t % CE4;
        unsigned pix = t / CE4;
        unsigned b = pix / PIX;
        int m = inst[pix];
        float4 v = compsrc[t];
        float* dst = comp + ((unsigned)(b * MAXINS + m)) * CE + e4 * 4;
        atomicAdd(dst + 0, v.x);
        atomicAdd(dst + 1, v.y);
        atomicAdd(dst + 2, v.z);
        atomicAdd(dst + 3, v.w);
    }
}

// ============ K3: inflate ================================================

__global__ void inflate_kernel(const int* __restrict__ inst,
                               const float4* __restrict__ comp,
                               float4* __restrict__ out) {
    const unsigned total = BZ * PIX * CE4;
    for (unsigned t = blockIdx.x * blockDim.x + threadIdx.x; t < total;
         t += gridDim.x * blockDim.x) {
        unsigned e4 = t % CE4;
        unsigned pix = t / CE4;
        unsigned b = pix / PIX;
        int m = inst[pix];
        out[t] = comp[((unsigned)(b * MAXINS + m)) * CE4 + e4];  // L2-hot gather
    }
}

extern "C" void kernel_launch(void* const* d_in, const int* in_sizes, int n_in,
                              void* d_out, int out_size, void* d_ws, size_t ws_size,
                              hipStream_t stream) {
    const int*    inst     = (const int*)d_in[0];      // (BZ,1,H,W) int32
    const float*  compsrc  = (const float*)d_in[1];    // (BZ,H,W,6,6) f32
    const int*    batchidx = (const int*)d_in[2];      // (BZ,MAXINS) int32
    const float*  selsrc   = (const float*)d_in[3];    // (BZ,MAXINS,CAND,6,6) f32
    float*        out      = (float*)d_out;            // (BZ,H,W,6,6) f32
    float*        comp     = (float*)d_ws;             // 115.2 KB @ ws[0]

    if (ws_size >= (size_t)COMP_BYTES + PART_BYTES) {
        // --- main path: barrier-light counting-sort compress ---
        float4* partials = (float4*)(comp + COMP_FLOATS);
        compress_sort_kernel<<<NBLK, TPB, 0, stream>>>(inst, (const float4*)compsrc,
                                                       partials);
        reduce_priv_kernel<<<(COMP_FLOATS / 4 + 255) / 256, 256, 0, stream>>>(
            partials, batchidx, (const float4*)selsrc, (float4*)comp);
    } else {
        // --- fallback: direct atomics into comp ---
        const int total = BZ * MAXINS * CE4;
        init_sel_kernel<<<(total + 255) / 256, 256, 0, stream>>>(
            batchidx, (const float4*)selsrc, (float4*)comp);
        compress_direct_kernel<<<2048, 256, 0, stream>>>(inst, (const float4*)compsrc,
                                                         comp);
    }

    // K3: inflate comp back to per-pixel output
    inflate_kernel<<<2048, 256, 0, stream>>>(inst, (const float4*)comp, (float4*)out);
}